// Round 6
// baseline (322.214 us; speedup 1.0000x reference)
//
#include <hip/hip_runtime.h>
#include <hip/hip_bf16.h>

#define N_NODES 50000
#define N_EDGES 800000
#define IN_F 256
#define HEADS 8
#define OUT_F 32
#define HF (HEADS * OUT_F)   // 256
#define SLOPE 0.2f

typedef __attribute__((ext_vector_type(8))) short bf16x8;
typedef __attribute__((ext_vector_type(4))) float f32x4;

__device__ __forceinline__ ushort f2bf(float f) {
  union { float f; unsigned u; } x;
  x.f = f;
  unsigned r = x.u + 0x7FFFu + ((x.u >> 16) & 1u);  // RNE
  return (ushort)(r >> 16);
}
__device__ __forceinline__ float bf2f_lo(unsigned u) {
  union { unsigned u; float f; } x; x.u = u << 16; return x.f;
}
__device__ __forceinline__ float bf2f_hi(unsigned u) {
  union { unsigned u; float f; } x; x.u = u & 0xFFFF0000u; return x.f;
}
__device__ __forceinline__ unsigned pkbf(float a, float b) {
  __hip_bfloat162 t = __float22bfloat162_rn(make_float2(a, b));
  return *(unsigned*)&t;  // low ushort = a, high = b
}

// ---------------------------------------------------------------------------
// Kernel 1: Bt[n][k] = bf16(fc_w[k][n])  (256x256, tiny)
// ---------------------------------------------------------------------------
__global__ void transpose_w(const float* __restrict__ fc_w,
                            ushort* __restrict__ Bt) {
  const int n = blockIdx.x, k = threadIdx.x;
  Bt[n * IN_F + k] = f2bf(fc_w[(size_t)k * HF + n]);
}

// ---------------------------------------------------------------------------
// Kernel 2: CSR row_ptr from sorted dst via binary search
// ---------------------------------------------------------------------------
__global__ void rowptr_kernel(const int* __restrict__ dst,
                              int* __restrict__ row_ptr, int N, int E) {
  int i = blockIdx.x * blockDim.x + threadIdx.x;
  if (i > N) return;
  int lo = 0, hi = E;
  while (lo < hi) {
    int mid = (lo + hi) >> 1;
    if (dst[mid] < i) lo = mid + 1; else hi = mid;
  }
  row_ptr[i] = lo;
}

// ---------------------------------------------------------------------------
// Kernel 3: register-resident-B MFMA GEMM, software-pipelined A loads.
// featb[M,256](bf16) = bf16( feat[M,256](f32) @ Bt^T ).
// 512 thr = 8 waves; wave owns 16 cols (grid.y picks 128-col half); strip of
// 64 rows per block (grid.x); per wave: B slice (K=256) in 32 VGPRs, A loads
// prefetched one 8-load stage ahead. launch_bounds(512,4): VGPR cap 128 so
// the 8 in-flight float4 loads are NOT serialized by the register allocator.
// ---------------------------------------------------------------------------
#define STRIP 64

__global__ __launch_bounds__(512, 4) void gemm_regB(
    const float* __restrict__ feat, const ushort* __restrict__ Bt,
    ushort* __restrict__ Cb, int M) {
  const int t = threadIdx.x;
  const int wave = t >> 6, lane = t & 63;
  const int l16 = lane & 15, q = lane >> 4;
  const int n_base = blockIdx.y * 128 + wave * 16;

  // B fragments: lane (l16,q) holds B[k = kk*32 + q*8 + j][n = n_base+l16]
  bf16x8 bF[8];
#pragma unroll
  for (int kk = 0; kk < 8; ++kk)
    bF[kk] = *(const bf16x8*)&Bt[(size_t)(n_base + l16) * IN_F + kk * 32 + q * 8];

  const int m_strip = blockIdx.x * STRIP;
  const float* rbase = feat + (size_t)m_strip * IN_F + q * 8;

  if (m_strip + STRIP <= M) {
    // ---------------- fast path: fully in-bounds, pipelined ----------------
    float4 ab[8];
    {  // preload stage (mi=0, half=0)
      const float* ap = rbase + (size_t)l16 * IN_F;
      ab[0] = *(const float4*)(ap + 0);  ab[1] = *(const float4*)(ap + 4);
      ab[2] = *(const float4*)(ap + 32); ab[3] = *(const float4*)(ap + 36);
      ab[4] = *(const float4*)(ap + 64); ab[5] = *(const float4*)(ap + 68);
      ab[6] = *(const float4*)(ap + 96); ab[7] = *(const float4*)(ap + 100);
    }
#pragma unroll 1
    for (int mi = 0; mi < STRIP / 16; ++mi) {
      f32x4 acc = {};
      // ---- half 0: consume ab, prefetch (mi, half=1)
      bf16x8 aF[4];
#pragma unroll
      for (int i = 0; i < 4; ++i) {
        union { unsigned u[4]; bf16x8 v; } pk;
        pk.u[0] = pkbf(ab[2 * i].x, ab[2 * i].y);
        pk.u[1] = pkbf(ab[2 * i].z, ab[2 * i].w);
        pk.u[2] = pkbf(ab[2 * i + 1].x, ab[2 * i + 1].y);
        pk.u[3] = pkbf(ab[2 * i + 1].z, ab[2 * i + 1].w);
        aF[i] = pk.v;
      }
      {
        const float* ap = rbase + (size_t)(mi * 16 + l16) * IN_F + 128;
        ab[0] = *(const float4*)(ap + 0);  ab[1] = *(const float4*)(ap + 4);
        ab[2] = *(const float4*)(ap + 32); ab[3] = *(const float4*)(ap + 36);
        ab[4] = *(const float4*)(ap + 64); ab[5] = *(const float4*)(ap + 68);
        ab[6] = *(const float4*)(ap + 96); ab[7] = *(const float4*)(ap + 100);
      }
#pragma unroll
      for (int i = 0; i < 4; ++i)
        acc = __builtin_amdgcn_mfma_f32_16x16x32_bf16(aF[i], bF[i], acc, 0, 0, 0);

      // ---- half 1: consume ab, prefetch (mi+1, half=0)
#pragma unroll
      for (int i = 0; i < 4; ++i) {
        union { unsigned u[4]; bf16x8 v; } pk;
        pk.u[0] = pkbf(ab[2 * i].x, ab[2 * i].y);
        pk.u[1] = pkbf(ab[2 * i].z, ab[2 * i].w);
        pk.u[2] = pkbf(ab[2 * i + 1].x, ab[2 * i + 1].y);
        pk.u[3] = pkbf(ab[2 * i + 1].z, ab[2 * i + 1].w);
        aF[i] = pk.v;
      }
      if (mi < STRIP / 16 - 1) {
        const float* ap = rbase + (size_t)((mi + 1) * 16 + l16) * IN_F;
        ab[0] = *(const float4*)(ap + 0);  ab[1] = *(const float4*)(ap + 4);
        ab[2] = *(const float4*)(ap + 32); ab[3] = *(const float4*)(ap + 36);
        ab[4] = *(const float4*)(ap + 64); ab[5] = *(const float4*)(ap + 68);
        ab[6] = *(const float4*)(ap + 96); ab[7] = *(const float4*)(ap + 100);
      }
#pragma unroll
      for (int i = 0; i < 4; ++i)
        acc = __builtin_amdgcn_mfma_f32_16x16x32_bf16(aF[i], bF[4 + i], acc, 0, 0, 0);

      // epilogue: C/D layout col=l16, row=q*4+r
      const int m0 = m_strip + mi * 16;
#pragma unroll
      for (int r = 0; r < 4; ++r)
        Cb[(size_t)(m0 + q * 4 + r) * HF + n_base + l16] = f2bf(acc[r]);
    }
  } else {
    // ---------------- tail path: predicated, simple ----------------
#pragma unroll 1
    for (int mi = 0; mi < STRIP / 16; ++mi) {
      const int row = m_strip + mi * 16 + l16;
      const float* ap = rbase + (size_t)(mi * 16 + l16) * IN_F;
      f32x4 acc = {};
#pragma unroll
      for (int kk = 0; kk < 8; ++kk) {
        float4 a0 = make_float4(0.f, 0.f, 0.f, 0.f);
        float4 a1 = make_float4(0.f, 0.f, 0.f, 0.f);
        if (row < M) {
          a0 = *(const float4*)(ap + kk * 32);
          a1 = *(const float4*)(ap + kk * 32 + 4);
        }
        union { unsigned u[4]; bf16x8 v; } pk;
        pk.u[0] = pkbf(a0.x, a0.y); pk.u[1] = pkbf(a0.z, a0.w);
        pk.u[2] = pkbf(a1.x, a1.y); pk.u[3] = pkbf(a1.z, a1.w);
        acc = __builtin_amdgcn_mfma_f32_16x16x32_bf16(pk.v, bF[kk], acc, 0, 0, 0);
      }
      const int m0 = m_strip + mi * 16;
#pragma unroll
      for (int r = 0; r < 4; ++r) {
        const int orow = m0 + q * 4 + r;
        if (orow < M)
          Cb[(size_t)orow * HF + n_base + l16] = f2bf(acc[r]);
      }
    }
  }
}

// ---------------------------------------------------------------------------
// Kernel 4: el[n,h] = sum_f bf16(feat_src)[n,h,f] * attn_l[h,f]
// ---------------------------------------------------------------------------
__global__ __launch_bounds__(256) void scores_kernel(
    const ushort* __restrict__ featb, const float* __restrict__ attn_l,
    float* __restrict__ el, int NH) {
  const int idx = blockIdx.x * blockDim.x + threadIdx.x;
  if (idx >= NH) return;
  const int h = idx & 7;
  const ushort* fp = &featb[(size_t)(idx >> 3) * HF + h * OUT_F];
  const float* ap = &attn_l[h * OUT_F];
  float acc = 0.f;
#pragma unroll
  for (int fq = 0; fq < OUT_F; fq += 8) {
    uint4 d = *(const uint4*)&fp[fq];
    float4 w0 = *(const float4*)&ap[fq];
    float4 w1 = *(const float4*)&ap[fq + 4];
    acc += bf2f_lo(d.x) * w0.x + bf2f_hi(d.x) * w0.y +
           bf2f_lo(d.y) * w0.z + bf2f_hi(d.y) * w0.w +
           bf2f_lo(d.z) * w1.x + bf2f_hi(d.z) * w1.y +
           bf2f_lo(d.w) * w1.z + bf2f_hi(d.w) * w1.w;
  }
  el[idx] = acc;
}

// ---------------------------------------------------------------------------
// Kernel 5: per-destination softmax + aggregation, block per node.
// Wave-parallel reductions (shfl over the 8 j-slots per wave + 4-way LDS
// combine), feature pass padded to 32-edge groups -> 4 independent 512 B
// gathers in flight per half-wave before the FMA block.
// ---------------------------------------------------------------------------
#define CAP 128

__global__ __launch_bounds__(256, 8) void aggregate_kernel(
    const ushort* __restrict__ featb, const float* __restrict__ el,
    const int* __restrict__ src, const int* __restrict__ row_ptr,
    float* __restrict__ out) {
  const int v = blockIdx.x;
  const int t = threadIdx.x;
  const int lane = t & 63, w = t >> 6;
  const int beg = row_ptr[v];
  const int deg = row_ptr[v + 1] - beg;

  if (deg == 0) {  // segment_sum over empty segment = 0
    out[(size_t)v * HF + t] = 0.f;
    return;
  }

  __shared__ float s_el[CAP][HEADS];     // 4 KB
  __shared__ float s_alpha[CAP][HEADS];  // 4 KB
  __shared__ int s_src[CAP];             // 0.5 KB
  __shared__ float s_wred[4][HEADS];     // 128 B
  __shared__ float s_m[HEADS];
  __shared__ float s_red[4][HF];         // 4 KB

  const int h8 = t & 7;
  const int j = t >> 3;  // 0..31 (within wave: j = w*8 + (lane>>3))

  // Phase 1: gather el (+src) into LDS (c<CAP), wave-reduce running max
  float mx = -1e30f;
  for (int c = j; c < deg; c += 32) {
    int s = src[beg + c];
    float e = el[s * HEADS + h8];
    if (c < CAP) {
      s_el[c][h8] = e;
      if (h8 == 0) s_src[c] = s;
    }
    mx = fmaxf(mx, e);
  }
  mx = fmaxf(mx, __shfl_xor(mx, 8, 64));
  mx = fmaxf(mx, __shfl_xor(mx, 16, 64));
  mx = fmaxf(mx, __shfl_xor(mx, 32, 64));
  if (lane < 8) s_wred[w][lane] = mx;
  __syncthreads();
  if (t < 8)
    s_m[t] = fmaxf(fmaxf(s_wred[0][t], s_wred[1][t]),
                   fmaxf(s_wred[2][t], s_wred[3][t]));
  __syncthreads();
  const float m = s_m[h8];

  // Phase 2: chunked alpha + feature accumulation (normalize at the end)
  const int half = lane >> 5;
  const int myh = (lane & 31) >> 2;   // head of this lane's facc slice
  const int fo = (lane & 31) * 8;     // 8-elem feature slice owned
  const int eoff = w * 2 + half;      // 0..7: edge slot within a group of 8
  float facc[8] = {};
  float ssum = 0.f;

  for (int c0 = 0; c0 < deg; c0 += CAP) {
    const int cn = min(CAP, deg - c0);
    const int cpad = (cn + 31) & ~31;  // pad gathers hit row 0 (L2-resident)

    if (c0 == 0) {  // common path: alphas from LDS-cached el
      for (int c = j; c < cn; c += 32) {
        float z = s_el[c][h8] - m;
        float zz = (z >= 0.f) ? z : SLOPE * z;
        float cf = __expf(zz);
        s_alpha[c][h8] = cf;
        ssum += cf;
      }
    } else {  // rare chunked path: re-gather from global
      __syncthreads();  // previous chunk's readers done
      for (int c = j; c < cn; c += 32) {
        int s = src[beg + c0 + c];
        if (h8 == 0) s_src[c] = s;
        float z = el[s * HEADS + h8] - m;
        float zz = (z >= 0.f) ? z : SLOPE * z;
        float cf = __expf(zz);
        s_alpha[c][h8] = cf;
        ssum += cf;
      }
    }
    for (int c = cn + j; c < cpad; c += 32) {  // zero pad slots
      s_alpha[c][h8] = 0.f;
      if (h8 == 0) s_src[c] = 0;
    }
    __syncthreads();

    // feature pass: 4 independent row gathers per iteration
    for (int c = eoff; c + 24 < cpad; c += 32) {
      const int s0 = s_src[c], s1 = s_src[c + 8];
      const int s2 = s_src[c + 16], s3 = s_src[c + 24];
      const float a0 = s_alpha[c][myh], a1 = s_alpha[c + 8][myh];
      const float a2 = s_alpha[c + 16][myh], a3 = s_alpha[c + 24][myh];
      const uint4 d0 = *(const uint4*)&featb[(size_t)s0 * HF + fo];
      const uint4 d1 = *(const uint4*)&featb[(size_t)s1 * HF + fo];
      const uint4 d2 = *(const uint4*)&featb[(size_t)s2 * HF + fo];
      const uint4 d3 = *(const uint4*)&featb[(size_t)s3 * HF + fo];
      facc[0] = fmaf(a0, bf2f_lo(d0.x), facc[0]);
      facc[1] = fmaf(a0, bf2f_hi(d0.x), facc[1]);
      facc[2] = fmaf(a0, bf2f_lo(d0.y), facc[2]);
      facc[3] = fmaf(a0, bf2f_hi(d0.y), facc[3]);
      facc[4] = fmaf(a0, bf2f_lo(d0.z), facc[4]);
      facc[5] = fmaf(a0, bf2f_hi(d0.z), facc[5]);
      facc[6] = fmaf(a0, bf2f_lo(d0.w), facc[6]);
      facc[7] = fmaf(a0, bf2f_hi(d0.w), facc[7]);
      facc[0] = fmaf(a1, bf2f_lo(d1.x), facc[0]);
      facc[1] = fmaf(a1, bf2f_hi(d1.x), facc[1]);
      facc[2] = fmaf(a1, bf2f_lo(d1.y), facc[2]);
      facc[3] = fmaf(a1, bf2f_hi(d1.y), facc[3]);
      facc[4] = fmaf(a1, bf2f_lo(d1.z), facc[4]);
      facc[5] = fmaf(a1, bf2f_hi(d1.z), facc[5]);
      facc[6] = fmaf(a1, bf2f_lo(d1.w), facc[6]);
      facc[7] = fmaf(a1, bf2f_hi(d1.w), facc[7]);
      facc[0] = fmaf(a2, bf2f_lo(d2.x), facc[0]);
      facc[1] = fmaf(a2, bf2f_hi(d2.x), facc[1]);
      facc[2] = fmaf(a2, bf2f_lo(d2.y), facc[2]);
      facc[3] = fmaf(a2, bf2f_hi(d2.y), facc[3]);
      facc[4] = fmaf(a2, bf2f_lo(d2.z), facc[4]);
      facc[5] = fmaf(a2, bf2f_hi(d2.z), facc[5]);
      facc[6] = fmaf(a2, bf2f_lo(d2.w), facc[6]);
      facc[7] = fmaf(a2, bf2f_hi(d2.w), facc[7]);
      facc[0] = fmaf(a3, bf2f_lo(d3.x), facc[0]);
      facc[1] = fmaf(a3, bf2f_hi(d3.x), facc[1]);
      facc[2] = fmaf(a3, bf2f_lo(d3.y), facc[2]);
      facc[3] = fmaf(a3, bf2f_hi(d3.y), facc[3]);
      facc[4] = fmaf(a3, bf2f_lo(d3.z), facc[4]);
      facc[5] = fmaf(a3, bf2f_hi(d3.z), facc[5]);
      facc[6] = fmaf(a3, bf2f_lo(d3.w), facc[6]);
      facc[7] = fmaf(a3, bf2f_hi(d3.w), facc[7]);
    }
    __syncthreads();  // readers done before next chunk overwrites
  }

  // final: wave-reduce ssum, combine half-wave facc, one barrier, store
  ssum += __shfl_xor(ssum, 8, 64);
  ssum += __shfl_xor(ssum, 16, 64);
  ssum += __shfl_xor(ssum, 32, 64);
  if (lane < 8) s_wred[w][lane] = ssum;
#pragma unroll
  for (int i = 0; i < 8; ++i) facc[i] += __shfl_xor(facc[i], 32, 64);
  if (lane < 32) {
    *(float4*)&s_red[w][fo] = make_float4(facc[0], facc[1], facc[2], facc[3]);
    *(float4*)&s_red[w][fo + 4] =
        make_float4(facc[4], facc[5], facc[6], facc[7]);
  }
  __syncthreads();

  const int oh = t >> 5;
  const float denom =
      s_wred[0][oh] + s_wred[1][oh] + s_wred[2][oh] + s_wred[3][oh];
  const float o = s_red[0][t] + s_red[1][t] + s_red[2][t] + s_red[3][t];
  out[(size_t)v * HF + t] = o / denom;
}

// ---------------------------------------------------------------------------
extern "C" void kernel_launch(void* const* d_in, const int* in_sizes, int n_in,
                              void* d_out, int out_size, void* d_ws,
                              size_t ws_size, hipStream_t stream) {
  const float* feat = (const float*)d_in[0];
  const float* fc_w = (const float*)d_in[1];
  const float* attn_l = (const float*)d_in[2];
  // d_in[3] = attn_r: unused — cancels exactly in the edge softmax.
  const int* src = (const int*)d_in[4];
  const int* dst = (const int*)d_in[5];
  float* out = (float*)d_out;

  const int N = N_NODES;
  const int E = N_EDGES;

  // workspace layout (~27.5 MB)
  ushort* featb = (ushort*)d_ws;                    // N*256 bf16  (25.6 MB)
  float* el = (float*)(featb + (size_t)N * HF);     // N*8 f32     (1.6 MB)
  ushort* Bt = (ushort*)(el + (size_t)N * HEADS);   // 256*256 bf16 (128 KB)
  int* row_ptr = (int*)(Bt + (size_t)IN_F * HF);    // N+1 ints

  transpose_w<<<HF, IN_F, 0, stream>>>(fc_w, Bt);
  rowptr_kernel<<<(N + 1 + 255) / 256, 256, 0, stream>>>(dst, row_ptr, N, E);

  dim3 gg((N + STRIP - 1) / STRIP, 2);
  gemm_regB<<<gg, 512, 0, stream>>>(feat, Bt, featb, N);

  scores_kernel<<<(N * HEADS + 255) / 256, 256, 0, stream>>>(featb, attn_l,
                                                             el, N * HEADS);

  aggregate_kernel<<<N, 256, 0, stream>>>(featb, el, src, row_ptr, out);
}